// Round 3
// baseline (1251.858 us; speedup 1.0000x reference)
//
#include <hip/hip_runtime.h>
#include <hip/hip_bf16.h>
#include <hip/hip_fp16.h>

typedef _Float16 h2vec __attribute__((ext_vector_type(2)));

static __device__ __forceinline__ float fast_sigmoid(float x) {
  return __builtin_amdgcn_rcpf(1.f + __expf(-x));
}
static __device__ __forceinline__ float fast_tanh(float x) {
  return 1.f - 2.f * __builtin_amdgcn_rcpf(__expf(2.f * x) + 1.f);
}
static __device__ __forceinline__ float fdot2u(unsigned int a, unsigned int b, float c) {
#if __has_builtin(__builtin_amdgcn_fdot2)
  return __builtin_amdgcn_fdot2(__builtin_bit_cast(h2vec, a),
                                __builtin_bit_cast(h2vec, b), c, false);
#else
  h2vec av = __builtin_bit_cast(h2vec, a);
  h2vec bv = __builtin_bit_cast(h2vec, b);
  return c + (float)av[0] * (float)bv[0] + (float)av[1] * (float)bv[1];
#endif
}
template<int CTRL>
static __device__ __forceinline__ float dpp_add(float v) {
  int x = __builtin_bit_cast(int, v);
  int y = __builtin_amdgcn_update_dpp(0, x, CTRL, 0xF, 0xF, true);
  return v + __builtin_bit_cast(float, y);
}
template<int CTRL>
static __device__ __forceinline__ float dpp_mov(float v) {
  int x = __builtin_bit_cast(int, v);
  int y = __builtin_amdgcn_update_dpp(0, x, CTRL, 0xF, 0xF, true);
  return __builtin_bit_cast(float, y);
}

// ---------------------------------------------------------------------------
// Generic fp32 GEMM with fused bias + activation epilogue.
// C[M,N] = act(A[M,K] @ W[N,K]^T + bias)
// MODE 0: val + b0[n] + b1[n]; MODE 1: relu(val + b0[n]); MODE 2: tanh(val + b0[n])
// ---------------------------------------------------------------------------
template<int BM, int BN, int BK, int TM, int TN, int MODE>
__global__ __launch_bounds__(256) void gemm_bias_act(
    const float* __restrict__ A, const float* __restrict__ W,
    const float* __restrict__ b0, const float* __restrict__ b1,
    float* __restrict__ C, int M, int N, int K) {
  static_assert(BM == BN, "loader assumes square tile");
  static_assert(BM * BK == 1024, "one float4 per thread");
  __shared__ float As[BK][BM];
  __shared__ float Ws[BK][BN];
  const int tid = threadIdx.x;
  const int m0 = blockIdx.x * BM, n0 = blockIdx.y * BN;
  constexpr int KQ = BK / 4;
  const int lm = tid / KQ;
  const int lk = (tid % KQ) * 4;
  const int tx = tid % (BN / TN);
  const int ty = tid / (BN / TN);
  float acc[TM][TN] = {};

  for (int k0 = 0; k0 < K; k0 += BK) {
    float4 av = *reinterpret_cast<const float4*>(A + (size_t)(m0 + lm) * K + k0 + lk);
    float4 wv = *reinterpret_cast<const float4*>(W + (size_t)(n0 + lm) * K + k0 + lk);
    As[lk + 0][lm] = av.x; As[lk + 1][lm] = av.y; As[lk + 2][lm] = av.z; As[lk + 3][lm] = av.w;
    Ws[lk + 0][lm] = wv.x; Ws[lk + 1][lm] = wv.y; Ws[lk + 2][lm] = wv.z; Ws[lk + 3][lm] = wv.w;
    __syncthreads();
#pragma unroll
    for (int k = 0; k < BK; ++k) {
      float a[TM], b[TN];
#pragma unroll
      for (int i = 0; i < TM / 4; ++i)
        *reinterpret_cast<float4*>(&a[i * 4]) =
            *reinterpret_cast<const float4*>(&As[k][ty * TM + i * 4]);
#pragma unroll
      for (int i = 0; i < TN / 4; ++i)
        *reinterpret_cast<float4*>(&b[i * 4]) =
            *reinterpret_cast<const float4*>(&Ws[k][tx * TN + i * 4]);
#pragma unroll
      for (int i = 0; i < TM; ++i)
#pragma unroll
        for (int jj = 0; jj < TN; ++jj) acc[i][jj] += a[i] * b[jj];
    }
    __syncthreads();
  }

#pragma unroll
  for (int i = 0; i < TM; ++i) {
    const int m = m0 + ty * TM + i;
#pragma unroll
    for (int jq = 0; jq < TN / 4; ++jq) {
      float4 v;
      float* vp = &v.x;
#pragma unroll
      for (int u = 0; u < 4; ++u) {
        const int n = n0 + tx * TN + jq * 4 + u;
        float val = acc[i][jq * 4 + u];
        if (MODE == 0) {
          val += b0[n] + b1[n];
        } else if (MODE == 1) {
          val = fmaxf(val + b0[n], 0.f);
        } else {
          val = fast_tanh(val + b0[n]);
        }
        vp[u] = val;
      }
      *reinterpret_cast<float4*>(C + (size_t)m * N + n0 + tx * TN + jq * 4) = v;
    }
  }
}

// ---------------------------------------------------------------------------
// LSTM recurrence, v3. One 512-thread block per batch; tid<256 = forward dir,
// tid>=256 = backward dir (2 independent sequences -> 2 waves/SIMD for
// latency hiding). Within a sequence: thread (j2 = ltid>>2, kq = ltid&3)
// computes 8 gate-rows over k-quarter kq, weights as f16x2 in VGPRs.
// h in LDS as f16x2 (padded bank-disjoint chunks, double-buffered, one
// barrier/step). Quad butterfly (DPP) reduces partials; then each quad-lane
// activates only ITS gate (tanh via 2*sigmoid(2x)-1, predicated, no
// divergence) and the 4 activations are redistributed with quad_perm
// broadcasts. Dots via v_dot2_f32_f16 (fp32 accumulate).
// ---------------------------------------------------------------------------
__global__ __launch_bounds__(512, 2) void lstm_seq3(
    const float* __restrict__ xg_f, const float* __restrict__ xg_b,
    const float* __restrict__ Whh_f, const float* __restrict__ Whh_b,
    float* __restrict__ out) {
  const int b = blockIdx.x;
  const int tid = threadIdx.x;
  const int seq = tid >> 8;       // 0 = forward, 1 = backward
  const int ltid = tid & 255;
  const int j2 = ltid >> 2;       // 0..63 unit pair
  const int kq = ltid & 3;        // k quarter
  const float* __restrict__ xg  = seq ? xg_b : xg_f;
  const float* __restrict__ Whh = seq ? Whh_b : Whh_f;

  __shared__ unsigned int hbuf[2][2][80];  // [seq][buf][chunk*20 + dword]

  // Load + convert weights: w[g][u][kk] covers k = kq*32 + 2*kk .. +1
  unsigned int w[4][2][16];
#pragma unroll
  for (int g = 0; g < 4; ++g)
#pragma unroll
    for (int u = 0; u < 2; ++u) {
      const float4* wr = reinterpret_cast<const float4*>(
          Whh + (size_t)(g * 128 + 2 * j2 + u) * 128 + kq * 32);
#pragma unroll
      for (int q = 0; q < 8; ++q) {
        float4 v = wr[q];
        __half2 p0 = __floats2half2_rn(v.x, v.y);
        __half2 p1 = __floats2half2_rn(v.z, v.w);
        w[g][u][2 * q]     = __builtin_bit_cast(unsigned int, p0);
        w[g][u][2 * q + 1] = __builtin_bit_cast(unsigned int, p1);
      }
    }

  if (tid < 320) reinterpret_cast<unsigned int*>(hbuf)[tid] = 0u;
  float c0 = 0.f, c1 = 0.f;
  __syncthreads();

  const int tt0 = seq ? 511 : 0;
  const int stp = seq ? -1 : 1;
  const size_t base = (size_t)b * 512 * 512;
  const int xoff = kq * 128 + 2 * j2;
  const bool writer = (kq == (j2 >> 4));
  const int wdst = (j2 >> 4) * 20 + (j2 & 15);

  float2 xv = *reinterpret_cast<const float2*>(xg + base + (size_t)tt0 * 512 + xoff);

  for (int t = 0; t < 512; ++t) {
    const int tt = tt0 + stp * t;

    // read my h chunk (broadcast among 16 lanes, 4 bank-disjoint addresses)
    const unsigned int* hc = &hbuf[seq][t & 1][kq * 20];
    uint4 q0 = reinterpret_cast<const uint4*>(hc)[0];
    uint4 q1 = reinterpret_cast<const uint4*>(hc)[1];
    uint4 q2 = reinterpret_cast<const uint4*>(hc)[2];
    uint4 q3 = reinterpret_cast<const uint4*>(hc)[3];
    unsigned int ha[16];
    ha[0] = q0.x; ha[1] = q0.y; ha[2] = q0.z; ha[3] = q0.w;
    ha[4] = q1.x; ha[5] = q1.y; ha[6] = q1.z; ha[7] = q1.w;
    ha[8] = q2.x; ha[9] = q2.y; ha[10] = q2.z; ha[11] = q2.w;
    ha[12] = q3.x; ha[13] = q3.y; ha[14] = q3.z; ha[15] = q3.w;

    // prefetch next step's xg (overlaps with dot2 chain)
    float2 xn = make_float2(0.f, 0.f);
    if (t + 1 < 512)
      xn = *reinterpret_cast<const float2*>(xg + base + (size_t)(tt + stp) * 512 + xoff);

    // accumulators; lane kq seeds gate g==kq with xg (added exactly once per row)
    float acc[4][2];
#pragma unroll
    for (int g = 0; g < 4; ++g) {
      acc[g][0] = (g == kq) ? xv.x : 0.f;
      acc[g][1] = (g == kq) ? xv.y : 0.f;
    }
#pragma unroll
    for (int kk = 0; kk < 16; ++kk) {
#pragma unroll
      for (int g = 0; g < 4; ++g) {
        acc[g][0] = fdot2u(w[g][0][kk], ha[kk], acc[g][0]);
        acc[g][1] = fdot2u(w[g][1][kk], ha[kk], acc[g][1]);
      }
    }
    // butterfly across the 4 kq lanes (quad): all lanes get identical sums
#pragma unroll
    for (int g = 0; g < 4; ++g)
#pragma unroll
      for (int u = 0; u < 2; ++u) {
        float a = acc[g][u];
        a = dpp_add<0xB1>(a);  // quad_perm [1,0,3,2]  (xor 1)
        a = dpp_add<0x4E>(a);  // quad_perm [2,3,0,1]  (xor 2)
        acc[g][u] = a;
      }

    // each quad-lane activates only its own gate, then quad_perm broadcast.
    // tanh(x) = 2*sigmoid(2x)-1 so all lanes run identical sigmoid code.
    float h0, h1;
    {
      // u = 0
      float a = acc[0][0];
      a = (kq == 1) ? acc[1][0] : a;
      a = (kq == 2) ? acc[2][0] : a;
      a = (kq == 3) ? acc[3][0] : a;
      float xs = (kq == 2) ? 2.f * a : a;
      float y = fast_sigmoid(xs);
      float act = (kq == 2) ? 2.f * y - 1.f : y;
      float gi = dpp_mov<0x00>(act);
      float gf = dpp_mov<0x55>(act);
      float gg = dpp_mov<0xAA>(act);
      float go = dpp_mov<0xFF>(act);
      c0 = gf * c0 + gi * gg;
      h0 = go * (2.f * fast_sigmoid(2.f * c0) - 1.f);
    }
    {
      // u = 1
      float a = acc[0][1];
      a = (kq == 1) ? acc[1][1] : a;
      a = (kq == 2) ? acc[2][1] : a;
      a = (kq == 3) ? acc[3][1] : a;
      float xs = (kq == 2) ? 2.f * a : a;
      float y = fast_sigmoid(xs);
      float act = (kq == 2) ? 2.f * y - 1.f : y;
      float gi = dpp_mov<0x00>(act);
      float gf = dpp_mov<0x55>(act);
      float gg = dpp_mov<0xAA>(act);
      float go = dpp_mov<0xFF>(act);
      c1 = gf * c1 + gi * gg;
      h1 = go * (2.f * fast_sigmoid(2.f * c1) - 1.f);
    }

    if (writer) {
      __half2 hp = __floats2half2_rn(h0, h1);
      hbuf[seq][(t + 1) & 1][wdst] = __builtin_bit_cast(unsigned int, hp);
      *reinterpret_cast<float2*>(out + ((size_t)b * 512 + tt) * 256 + seq * 128 + 2 * j2)
          = make_float2(h0, h1);
    }
    xv = xn;
    __syncthreads();
  }
}

// ---------------------------------------------------------------------------
// Launcher
// ---------------------------------------------------------------------------
extern "C" void kernel_launch(void* const* d_in, const int* in_sizes, int n_in,
                              void* d_out, int out_size, void* d_ws, size_t ws_size,
                              hipStream_t stream) {
  (void)in_sizes; (void)n_in; (void)out_size; (void)ws_size;

  const float* x     = (const float*)d_in[0];
  const float* Wih00 = (const float*)d_in[1];
  const float* Whh00 = (const float*)d_in[2];
  const float* bih00 = (const float*)d_in[3];
  const float* bhh00 = (const float*)d_in[4];
  const float* Wih01 = (const float*)d_in[5];
  const float* Whh01 = (const float*)d_in[6];
  const float* bih01 = (const float*)d_in[7];
  const float* bhh01 = (const float*)d_in[8];
  const float* Wih10 = (const float*)d_in[9];
  const float* Whh10 = (const float*)d_in[10];
  const float* bih10 = (const float*)d_in[11];
  const float* bhh10 = (const float*)d_in[12];
  const float* Wih11 = (const float*)d_in[13];
  const float* Whh11 = (const float*)d_in[14];
  const float* bih11 = (const float*)d_in[15];
  const float* bhh11 = (const float*)d_in[16];
  const float* W1 = (const float*)d_in[17];
  const float* b1 = (const float*)d_in[18];
  const float* W2 = (const float*)d_in[19];
  const float* b2 = (const float*)d_in[20];
  float* out = (float*)d_out;

  char* ws = (char*)d_ws;
  float* xg_fw = (float*)ws;                          // 64 MB  [B,T,512]
  float* xg_bw = (float*)(ws + ((size_t)64 << 20));   // 64 MB  [B,T,512]
  float* buf   = (float*)(ws + ((size_t)128 << 20));  // 32 MB  [B,T,256]

  const int M = 64 * 512;  // 32768 rows

  // ---- layer 0 ----
  gemm_bias_act<128, 128, 8, 8, 8, 0><<<dim3(M / 128, 4), 256, 0, stream>>>(
      x, Wih00, bih00, bhh00, xg_fw, M, 512, 64);
  gemm_bias_act<128, 128, 8, 8, 8, 0><<<dim3(M / 128, 4), 256, 0, stream>>>(
      x, Wih01, bih01, bhh01, xg_bw, M, 512, 64);
  lstm_seq3<<<dim3(64), 512, 0, stream>>>(xg_fw, xg_bw, Whh00, Whh01, buf);

  // ---- layer 1 ----
  gemm_bias_act<128, 128, 8, 8, 8, 0><<<dim3(M / 128, 4), 256, 0, stream>>>(
      buf, Wih10, bih10, bhh10, xg_fw, M, 512, 256);
  gemm_bias_act<128, 128, 8, 8, 8, 0><<<dim3(M / 128, 4), 256, 0, stream>>>(
      buf, Wih11, bih11, bhh11, xg_bw, M, 512, 256);
  lstm_seq3<<<dim3(64), 512, 0, stream>>>(xg_fw, xg_bw, Whh10, Whh11, buf);

  // ---- head ----
  gemm_bias_act<128, 128, 8, 8, 8, 1><<<dim3(M / 128, 2), 256, 0, stream>>>(
      buf, W1, b1, nullptr, xg_fw, M, 256, 256);
  gemm_bias_act<64, 64, 16, 4, 4, 2><<<dim3(M / 64, 1), 256, 0, stream>>>(
      xg_fw, W2, b2, nullptr, out, M, 64, 256);
}

// Round 4
// 997.887 us; speedup vs baseline: 1.2545x; 1.2545x over previous
//
#include <hip/hip_runtime.h>
#include <hip/hip_bf16.h>
#include <hip/hip_fp16.h>

typedef _Float16 h2vec __attribute__((ext_vector_type(2)));

static __device__ __forceinline__ float fast_sigmoid(float x) {
  return __builtin_amdgcn_rcpf(1.f + __expf(-x));
}
static __device__ __forceinline__ float fast_tanh(float x) {
  return 1.f - 2.f * __builtin_amdgcn_rcpf(__expf(2.f * x) + 1.f);
}
static __device__ __forceinline__ float fdot2u(unsigned int a, unsigned int b, float c) {
#if __has_builtin(__builtin_amdgcn_fdot2)
  return __builtin_amdgcn_fdot2(__builtin_bit_cast(h2vec, a),
                                __builtin_bit_cast(h2vec, b), c, false);
#else
  h2vec av = __builtin_bit_cast(h2vec, a);
  h2vec bv = __builtin_bit_cast(h2vec, b);
  return c + (float)av[0] * (float)bv[0] + (float)av[1] * (float)bv[1];
#endif
}
template<int CTRL>
static __device__ __forceinline__ float dpp_add(float v) {
  int x = __builtin_bit_cast(int, v);
  int y = __builtin_amdgcn_update_dpp(0, x, CTRL, 0xF, 0xF, true);
  return v + __builtin_bit_cast(float, y);
}
template<int CTRL>
static __device__ __forceinline__ float dpp_mov(float v) {
  int x = __builtin_bit_cast(int, v);
  int y = __builtin_amdgcn_update_dpp(0, x, CTRL, 0xF, 0xF, true);
  return __builtin_bit_cast(float, y);
}

// ---------------------------------------------------------------------------
// Generic fp32 GEMM with fused bias + activation epilogue.
// C[M,N] = act(A[M,K] @ W[N,K]^T + bias)
// MODE 0: val + b0[n] + b1[n]; MODE 1: relu(val + b0[n]); MODE 2: tanh(val + b0[n])
// ---------------------------------------------------------------------------
template<int BM, int BN, int BK, int TM, int TN, int MODE>
__global__ __launch_bounds__(256) void gemm_bias_act(
    const float* __restrict__ A, const float* __restrict__ W,
    const float* __restrict__ b0, const float* __restrict__ b1,
    float* __restrict__ C, int M, int N, int K) {
  static_assert(BM == BN, "loader assumes square tile");
  static_assert(BM * BK == 1024, "one float4 per thread");
  __shared__ float As[BK][BM];
  __shared__ float Ws[BK][BN];
  const int tid = threadIdx.x;
  const int m0 = blockIdx.x * BM, n0 = blockIdx.y * BN;
  constexpr int KQ = BK / 4;
  const int lm = tid / KQ;
  const int lk = (tid % KQ) * 4;
  const int tx = tid % (BN / TN);
  const int ty = tid / (BN / TN);
  float acc[TM][TN] = {};

  for (int k0 = 0; k0 < K; k0 += BK) {
    float4 av = *reinterpret_cast<const float4*>(A + (size_t)(m0 + lm) * K + k0 + lk);
    float4 wv = *reinterpret_cast<const float4*>(W + (size_t)(n0 + lm) * K + k0 + lk);
    As[lk + 0][lm] = av.x; As[lk + 1][lm] = av.y; As[lk + 2][lm] = av.z; As[lk + 3][lm] = av.w;
    Ws[lk + 0][lm] = wv.x; Ws[lk + 1][lm] = wv.y; Ws[lk + 2][lm] = wv.z; Ws[lk + 3][lm] = wv.w;
    __syncthreads();
#pragma unroll
    for (int k = 0; k < BK; ++k) {
      float a[TM], b[TN];
#pragma unroll
      for (int i = 0; i < TM / 4; ++i)
        *reinterpret_cast<float4*>(&a[i * 4]) =
            *reinterpret_cast<const float4*>(&As[k][ty * TM + i * 4]);
#pragma unroll
      for (int i = 0; i < TN / 4; ++i)
        *reinterpret_cast<float4*>(&b[i * 4]) =
            *reinterpret_cast<const float4*>(&Ws[k][tx * TN + i * 4]);
#pragma unroll
      for (int i = 0; i < TM; ++i)
#pragma unroll
        for (int jj = 0; jj < TN; ++jj) acc[i][jj] += a[i] * b[jj];
    }
    __syncthreads();
  }

#pragma unroll
  for (int i = 0; i < TM; ++i) {
    const int m = m0 + ty * TM + i;
#pragma unroll
    for (int jq = 0; jq < TN / 4; ++jq) {
      float4 v;
      float* vp = &v.x;
#pragma unroll
      for (int u = 0; u < 4; ++u) {
        const int n = n0 + tx * TN + jq * 4 + u;
        float val = acc[i][jq * 4 + u];
        if (MODE == 0) {
          val += b0[n] + b1[n];
        } else if (MODE == 1) {
          val = fmaxf(val + b0[n], 0.f);
        } else {
          val = fast_tanh(val + b0[n]);
        }
        vp[u] = val;
      }
      *reinterpret_cast<float4*>(C + (size_t)m * N + n0 + tx * TN + jq * 4) = v;
    }
  }
}

// ---------------------------------------------------------------------------
// LSTM recurrence, v4. One 512-thread block per (batch, direction):
// 128 blocks -> 128 CUs, 8 waves/block = 2 waves/SIMD (latency hiding).
// Thread (j = tid>>2 unit 0..127, kq = tid&3 k-quarter) computes the 4
// gate-rows of unit j over k in [kq*32, kq*32+32): 64 dot2/thread.
// Quad-only DPP allreduce (xor1+xor2), lane kq activates gate kq
// (tanh via 2*sigmoid(2x)-1, select-predicated), quad_perm broadcasts
// redistribute the 4 gates. h stored as plain f16 in LDS (ds_write_b16),
// double-buffered, one barrier per step. xg prefetch depth 2.
// ---------------------------------------------------------------------------
__global__ __launch_bounds__(512, 2) void lstm_seq4(
    const float* __restrict__ xg_f, const float* __restrict__ xg_b,
    const float* __restrict__ Whh_f, const float* __restrict__ Whh_b,
    float* __restrict__ out) {
  const int b = blockIdx.x;
  const int dir = blockIdx.y;
  const int tid = threadIdx.x;
  const int j = tid >> 2;   // unit 0..127
  const int kq = tid & 3;   // k quarter
  const float* __restrict__ xg  = dir ? xg_b : xg_f;
  const float* __restrict__ Whh = dir ? Whh_b : Whh_f;

  __shared__ unsigned int hbuf[2][64];  // [buf][dword]: h as f16, h[2d],h[2d+1]

  // Weights: w[g][kk] = f16x2 of row (g*128+j), k = kq*32 + 2*kk, +1
  unsigned int w[4][16];
#pragma unroll
  for (int g = 0; g < 4; ++g) {
    const float4* wr = reinterpret_cast<const float4*>(
        Whh + (size_t)(g * 128 + j) * 128 + kq * 32);
#pragma unroll
    for (int q = 0; q < 8; ++q) {
      float4 v = wr[q];
      __half2 p0 = __floats2half2_rn(v.x, v.y);
      __half2 p1 = __floats2half2_rn(v.z, v.w);
      w[g][2 * q]     = __builtin_bit_cast(unsigned int, p0);
      w[g][2 * q + 1] = __builtin_bit_cast(unsigned int, p1);
    }
  }

  if (tid < 128) hbuf[tid >> 6][tid & 63] = 0u;
  float c = 0.f;
  __syncthreads();

  const int tt0 = dir ? 511 : 0;
  const int stp = dir ? -1 : 1;
  const size_t base = (size_t)b * 512 * 512;
  const int xidx = kq * 128 + j;  // the xg element this lane activates

  // prefetch depth 2
  float xv = xg[base + (size_t)tt0 * 512 + xidx];
  float xn = xg[base + (size_t)(tt0 + stp) * 512 + xidx];

  for (int t = 0; t < 512; ++t) {
    const int tt = tt0 + stp * t;

    // read my h quarter: 4 x ds_read_b128, broadcast among 16 lanes each
    const uint4* hc = reinterpret_cast<const uint4*>(&hbuf[t & 1][kq * 16]);
    uint4 q0 = hc[0], q1 = hc[1], q2 = hc[2], q3 = hc[3];
    unsigned int ha[16];
    ha[0] = q0.x; ha[1] = q0.y; ha[2] = q0.z; ha[3] = q0.w;
    ha[4] = q1.x; ha[5] = q1.y; ha[6] = q1.z; ha[7] = q1.w;
    ha[8] = q2.x; ha[9] = q2.y; ha[10] = q2.z; ha[11] = q2.w;
    ha[12] = q3.x; ha[13] = q3.y; ha[14] = q3.z; ha[15] = q3.w;

    // prefetch xg for t+2 (two steps of latency cover)
    float xn2 = 0.f;
    if (t + 2 < 512)
      xn2 = xg[base + (size_t)(tt + 2 * stp) * 512 + xidx];

    float acc[4] = {0.f, 0.f, 0.f, 0.f};
#pragma unroll
    for (int kk = 0; kk < 16; ++kk) {
#pragma unroll
      for (int g = 0; g < 4; ++g)
        acc[g] = fdot2u(w[g][kk], ha[kk], acc[g]);
    }

    // quad allreduce (lanes kq=0..3 hold k-quarter partials)
#pragma unroll
    for (int g = 0; g < 4; ++g) {
      float a = acc[g];
      a = dpp_add<0xB1>(a);  // xor 1
      a = dpp_add<0x4E>(a);  // xor 2
      acc[g] = a;
    }

    // lane kq activates gate kq (select-predicated, no divergence)
    float a = acc[0];
    a = (kq == 1) ? acc[1] : a;
    a = (kq == 2) ? acc[2] : a;
    a = (kq == 3) ? acc[3] : a;
    a += xv;
    const float xs = (kq == 2) ? 2.f * a : a;
    const float y = fast_sigmoid(xs);
    const float act = (kq == 2) ? 2.f * y - 1.f : y;

    // quad_perm broadcasts: every lane in the quad gets all 4 gates
    const float gi = dpp_mov<0x00>(act);
    const float gf = dpp_mov<0x55>(act);
    const float gg = dpp_mov<0xAA>(act);
    const float go = dpp_mov<0xFF>(act);

    c = gf * c + gi * gg;
    const float h = go * (2.f * fast_sigmoid(2.f * c) - 1.f);

    if (kq == 0) {  // write h[j] as f16 into next step's buffer
      unsigned short us = __builtin_bit_cast(unsigned short, (_Float16)h);
      reinterpret_cast<unsigned short*>(hbuf[(t + 1) & 1])[j] = us;
    }
    if (kq == 1) {  // write h[j] to global output (coalesced over j)
      out[((size_t)b * 512 + tt) * 256 + dir * 128 + j] = h;
    }

    xv = xn;
    xn = xn2;
    __syncthreads();
  }
}

// ---------------------------------------------------------------------------
// Launcher
// ---------------------------------------------------------------------------
extern "C" void kernel_launch(void* const* d_in, const int* in_sizes, int n_in,
                              void* d_out, int out_size, void* d_ws, size_t ws_size,
                              hipStream_t stream) {
  (void)in_sizes; (void)n_in; (void)out_size; (void)ws_size;

  const float* x     = (const float*)d_in[0];
  const float* Wih00 = (const float*)d_in[1];
  const float* Whh00 = (const float*)d_in[2];
  const float* bih00 = (const float*)d_in[3];
  const float* bhh00 = (const float*)d_in[4];
  const float* Wih01 = (const float*)d_in[5];
  const float* Whh01 = (const float*)d_in[6];
  const float* bih01 = (const float*)d_in[7];
  const float* bhh01 = (const float*)d_in[8];
  const float* Wih10 = (const float*)d_in[9];
  const float* Whh10 = (const float*)d_in[10];
  const float* bih10 = (const float*)d_in[11];
  const float* bhh10 = (const float*)d_in[12];
  const float* Wih11 = (const float*)d_in[13];
  const float* Whh11 = (const float*)d_in[14];
  const float* bih11 = (const float*)d_in[15];
  const float* bhh11 = (const float*)d_in[16];
  const float* W1 = (const float*)d_in[17];
  const float* b1 = (const float*)d_in[18];
  const float* W2 = (const float*)d_in[19];
  const float* b2 = (const float*)d_in[20];
  float* out = (float*)d_out;

  char* ws = (char*)d_ws;
  float* xg_fw = (float*)ws;                          // 64 MB  [B,T,512]
  float* xg_bw = (float*)(ws + ((size_t)64 << 20));   // 64 MB  [B,T,512]
  float* buf   = (float*)(ws + ((size_t)128 << 20));  // 32 MB  [B,T,256]

  const int M = 64 * 512;  // 32768 rows

  // ---- layer 0 ----
  gemm_bias_act<128, 128, 8, 8, 8, 0><<<dim3(M / 128, 4), 256, 0, stream>>>(
      x, Wih00, bih00, bhh00, xg_fw, M, 512, 64);
  gemm_bias_act<128, 128, 8, 8, 8, 0><<<dim3(M / 128, 4), 256, 0, stream>>>(
      x, Wih01, bih01, bhh01, xg_bw, M, 512, 64);
  lstm_seq4<<<dim3(64, 2), 512, 0, stream>>>(xg_fw, xg_bw, Whh00, Whh01, buf);

  // ---- layer 1 ----
  gemm_bias_act<128, 128, 8, 8, 8, 0><<<dim3(M / 128, 4), 256, 0, stream>>>(
      buf, Wih10, bih10, bhh10, xg_fw, M, 512, 256);
  gemm_bias_act<128, 128, 8, 8, 8, 0><<<dim3(M / 128, 4), 256, 0, stream>>>(
      buf, Wih11, bih11, bhh11, xg_bw, M, 512, 256);
  lstm_seq4<<<dim3(64, 2), 512, 0, stream>>>(xg_fw, xg_bw, Whh10, Whh11, buf);

  // ---- head ----
  gemm_bias_act<128, 128, 8, 8, 8, 1><<<dim3(M / 128, 2), 256, 0, stream>>>(
      buf, W1, b1, nullptr, xg_fw, M, 256, 256);
  gemm_bias_act<64, 64, 16, 4, 4, 2><<<dim3(M / 64, 1), 256, 0, stream>>>(
      xg_fw, W2, b2, nullptr, out, M, 64, 256);
}